// Round 1
// baseline (2571.265 us; speedup 1.0000x reference)
//
#include <hip/hip_runtime.h>
#include <cstdint>
#include <cstddef>

#define INP 2048
#define EMB 512
#define NHEAD 2
#define BSZ 16
#define SEQ 1024
#define LAMBDA 10.0f

// ---------------------------------------------------------------------------
// zero small accumulators (Z_row, Z_col, S21, S12): 4 * 32 * 1024 floats
// ---------------------------------------------------------------------------
__global__ __launch_bounds__(256) void zero_kernel(float* __restrict__ p, int n) {
    int i = blockIdx.x * 256 + threadIdx.x;
    if (i < n) p[i] = 0.f;
}

// ---------------------------------------------------------------------------
// Projection GEMM: Q[z][l][e] = sum_d img[b][d][l] * W[h][d][e] + bias[h][e]
//   z = (im*NHEAD + h)*BSZ + b
// A is K-major in memory already (img[b][d][l], d = K, l contiguous), and
// W[h][d][e] likewise (d = K, e contiguous) -> direct float4 stage into
// k-major LDS tiles, no transpose needed.
// grid: (SEQ/128, EMB/128, 2*NHEAD*BSZ) = (8, 4, 64), block 256
// ---------------------------------------------------------------------------
__global__ __launch_bounds__(256) void proj_kernel(
    const float* __restrict__ img1, const float* __restrict__ img2,
    const float* __restrict__ W, const float* __restrict__ bias,
    float* __restrict__ Q) {
    const int l0 = blockIdx.x * 128;
    const int e0 = blockIdx.y * 128;
    const int z  = blockIdx.z;
    const int b  = z % BSZ;
    const int h  = (z / BSZ) % NHEAD;
    const int im = z / (BSZ * NHEAD);

    const float* __restrict__ A  = (im == 0 ? img1 : img2) + (size_t)b * INP * SEQ;
    const float* __restrict__ Bw = W + (size_t)h * INP * EMB;

    __shared__ float As[8][132];   // pad 132 (mult of 4): aligned float4, spread banks
    __shared__ float Bs[8][132];

    const int t  = threadIdx.x;
    const int tx = t & 15;
    const int ty = t >> 4;
    const int lr = t >> 5;         // staging row 0..7
    const int lc = (t & 31) * 4;   // staging col 0..124

    float acc[8][8];
#pragma unroll
    for (int i = 0; i < 8; i++)
#pragma unroll
        for (int j = 0; j < 8; j++) acc[i][j] = 0.f;

    for (int k0 = 0; k0 < INP; k0 += 8) {
        float4 av = *(const float4*)(A  + (size_t)(k0 + lr) * SEQ + l0 + lc);
        float4 bv = *(const float4*)(Bw + (size_t)(k0 + lr) * EMB + e0 + lc);
        __syncthreads();
        *(float4*)&As[lr][lc] = av;
        *(float4*)&Bs[lr][lc] = bv;
        __syncthreads();
#pragma unroll
        for (int kk = 0; kk < 8; kk++) {
            float4 a0 = *(const float4*)&As[kk][ty * 8];
            float4 a1 = *(const float4*)&As[kk][ty * 8 + 4];
            float4 b0 = *(const float4*)&Bs[kk][tx * 8];
            float4 b1 = *(const float4*)&Bs[kk][tx * 8 + 4];
            float a[8]  = {a0.x, a0.y, a0.z, a0.w, a1.x, a1.y, a1.z, a1.w};
            float bb[8] = {b0.x, b0.y, b0.z, b0.w, b1.x, b1.y, b1.z, b1.w};
#pragma unroll
            for (int i = 0; i < 8; i++)
#pragma unroll
                for (int j = 0; j < 8; j++)
                    acc[i][j] = fmaf(a[i], bb[j], acc[i][j]);
        }
    }

    float* __restrict__ Qz = Q + (size_t)z * SEQ * EMB;
#pragma unroll
    for (int i = 0; i < 8; i++) {
        const int row = l0 + ty * 8 + i;
#pragma unroll
        for (int j = 0; j < 8; j += 4) {
            const int col = e0 + tx * 8 + j;
            float4 v;
            v.x = acc[i][j + 0] + bias[h * EMB + col + 0];
            v.y = acc[i][j + 1] + bias[h * EMB + col + 1];
            v.z = acc[i][j + 2] + bias[h * EMB + col + 2];
            v.w = acc[i][j + 3] + bias[h * EMB + col + 3];
            *(float4*)(Qz + (size_t)row * EMB + col) = v;
        }
    }
}

// ---------------------------------------------------------------------------
// In-place L2 row normalization: q / max(||q||, 1e-12), rows of EMB=512.
// grid: 2*NHEAD*BSZ*SEQ = 65536 blocks, 128 threads (4 floats each)
// ---------------------------------------------------------------------------
__global__ __launch_bounds__(128) void norm_kernel(float* __restrict__ Q) {
    const size_t row = blockIdx.x;
    float* p = Q + row * EMB;
    const int t = threadIdx.x;
    float4 v = *(float4*)(p + t * 4);
    float s = v.x * v.x + v.y * v.y + v.z * v.z + v.w * v.w;
#pragma unroll
    for (int o = 32; o > 0; o >>= 1) s += __shfl_down(s, o);
    __shared__ float ws2[2];
    if ((t & 63) == 0) ws2[t >> 6] = s;
    __syncthreads();
    const float total = ws2[0] + ws2[1];
    const float scale = 1.f / fmaxf(sqrtf(total), 1e-12f);
    v.x *= scale; v.y *= scale; v.z *= scale; v.w *= scale;
    *(float4*)(p + t * 4) = v;
}

// ---------------------------------------------------------------------------
// Attention pass. rel[l,m] = LAMBDA * dot(n1[l], n2[m]); E = exp(rel).
// MODE 0: Z_row[l] += sum_m E; Z_col[m] += sum_l E
// MODE 1: S21[l] += sum_m E / Z_col[m]; S12[m] += sum_l E / Z_row[l]
// Both n1, n2 are row-major (K=EMB contiguous) -> transpose-stage into
// k-major LDS tiles with scalar writes (2-way bank alias = free).
// grid: (SEQ/128, SEQ/128, NHEAD*BSZ) = (8, 8, 32), block 256
// ---------------------------------------------------------------------------
template <int MODE>
__global__ __launch_bounds__(256) void attn_kernel(
    const float* __restrict__ Q, float* __restrict__ Zr, float* __restrict__ Zc,
    float* __restrict__ S21, float* __restrict__ S12) {
    const int l0 = blockIdx.x * 128;
    const int m0 = blockIdx.y * 128;
    const int hb = blockIdx.z;
    const float* __restrict__ n1 = Q + (size_t)hb * SEQ * EMB;
    const float* __restrict__ n2 = Q + ((size_t)(NHEAD * BSZ) + hb) * SEQ * EMB;

    __shared__ float As[16][132];
    __shared__ float Bs[16][132];
    __shared__ float redR[128];
    __shared__ float redC[128];

    const int t  = threadIdx.x;
    const int tx = t & 15;
    const int ty = t >> 4;
    const int r  = t >> 1;        // staging row 0..127
    const int kc = (t & 1) * 8;   // staging k offset 0 or 8

    float acc[8][8];
#pragma unroll
    for (int i = 0; i < 8; i++)
#pragma unroll
        for (int j = 0; j < 8; j++) acc[i][j] = 0.f;

    for (int k0 = 0; k0 < EMB; k0 += 16) {
        float4 a0 = *(const float4*)(n1 + (size_t)(l0 + r) * EMB + k0 + kc);
        float4 a1 = *(const float4*)(n1 + (size_t)(l0 + r) * EMB + k0 + kc + 4);
        float4 b0 = *(const float4*)(n2 + (size_t)(m0 + r) * EMB + k0 + kc);
        float4 b1 = *(const float4*)(n2 + (size_t)(m0 + r) * EMB + k0 + kc + 4);
        __syncthreads();
        As[kc + 0][r] = a0.x; As[kc + 1][r] = a0.y; As[kc + 2][r] = a0.z; As[kc + 3][r] = a0.w;
        As[kc + 4][r] = a1.x; As[kc + 5][r] = a1.y; As[kc + 6][r] = a1.z; As[kc + 7][r] = a1.w;
        Bs[kc + 0][r] = b0.x; Bs[kc + 1][r] = b0.y; Bs[kc + 2][r] = b0.z; Bs[kc + 3][r] = b0.w;
        Bs[kc + 4][r] = b1.x; Bs[kc + 5][r] = b1.y; Bs[kc + 6][r] = b1.z; Bs[kc + 7][r] = b1.w;
        __syncthreads();
#pragma unroll
        for (int kk = 0; kk < 16; kk++) {
            float4 a0r = *(const float4*)&As[kk][ty * 8];
            float4 a1r = *(const float4*)&As[kk][ty * 8 + 4];
            float4 b0r = *(const float4*)&Bs[kk][tx * 8];
            float4 b1r = *(const float4*)&Bs[kk][tx * 8 + 4];
            float a[8]  = {a0r.x, a0r.y, a0r.z, a0r.w, a1r.x, a1r.y, a1r.z, a1r.w};
            float bb[8] = {b0r.x, b0r.y, b0r.z, b0r.w, b1r.x, b1r.y, b1r.z, b1r.w};
#pragma unroll
            for (int i = 0; i < 8; i++)
#pragma unroll
                for (int j = 0; j < 8; j++)
                    acc[i][j] = fmaf(a[i], bb[j], acc[i][j]);
        }
    }

    // E = exp(lambda * cos)
    float ev[8][8];
#pragma unroll
    for (int i = 0; i < 8; i++)
#pragma unroll
        for (int j = 0; j < 8; j++) ev[i][j] = expf(LAMBDA * acc[i][j]);

    if (t < 128) { redR[t] = 0.f; redC[t] = 0.f; }
    __syncthreads();

    float rs[8], cs[8];
#pragma unroll
    for (int i = 0; i < 8; i++) { rs[i] = 0.f; cs[i] = 0.f; }

    if (MODE == 0) {
#pragma unroll
        for (int i = 0; i < 8; i++)
#pragma unroll
            for (int j = 0; j < 8; j++) { rs[i] += ev[i][j]; cs[j] += ev[i][j]; }
    } else {
        float izr[8], izc[8];
#pragma unroll
        for (int i = 0; i < 8; i++) izr[i] = 1.f / Zr[hb * SEQ + l0 + ty * 8 + i];
#pragma unroll
        for (int j = 0; j < 8; j++) izc[j] = 1.f / Zc[hb * SEQ + m0 + tx * 8 + j];
#pragma unroll
        for (int i = 0; i < 8; i++)
#pragma unroll
            for (int j = 0; j < 8; j++) {
                rs[i] += ev[i][j] * izc[j];   // contribution to sim21[l]
                cs[j] += ev[i][j] * izr[i];   // contribution to sim12[m]
            }
    }

#pragma unroll
    for (int i = 0; i < 8; i++) atomicAdd(&redR[ty * 8 + i], rs[i]);
#pragma unroll
    for (int j = 0; j < 8; j++) atomicAdd(&redC[tx * 8 + j], cs[j]);
    __syncthreads();

    if (t < 128) {
        if (MODE == 0) {
            atomicAdd(&Zr[hb * SEQ + l0 + t], redR[t]);
            atomicAdd(&Zc[hb * SEQ + m0 + t], redC[t]);
        } else {
            atomicAdd(&S21[hb * SEQ + l0 + t], redR[t]);
            atomicAdd(&S12[hb * SEQ + m0 + t], redC[t]);
        }
    }
}

// ---------------------------------------------------------------------------
// Finalize: out[w][h][b][l] = S[l] / (sum_l S[l] + 1e-8), w=0 -> S21, w=1 -> S12
// grid: 2*NHEAD*BSZ = 64 blocks, 256 threads
// ---------------------------------------------------------------------------
__global__ __launch_bounds__(256) void fin_kernel(
    const float* __restrict__ S21, const float* __restrict__ S12,
    float* __restrict__ out) {
    const int z  = blockIdx.x;                // w*32 + hb
    const int w  = z / (NHEAD * BSZ);
    const int hb = z % (NHEAD * BSZ);
    const float* __restrict__ src = (w == 0 ? S21 : S12) + (size_t)hb * SEQ;
    const int t = threadIdx.x;

    float s = 0.f;
    for (int i = t; i < SEQ; i += 256) s += src[i];
#pragma unroll
    for (int o = 32; o > 0; o >>= 1) s += __shfl_down(s, o);
    __shared__ float red[4];
    if ((t & 63) == 0) red[t >> 6] = s;
    __syncthreads();
    const float total = red[0] + red[1] + red[2] + red[3];
    const float inv = 1.f / (total + 1e-8f);
    for (int i = t; i < SEQ; i += 256)
        out[(size_t)z * SEQ + i] = src[i] * inv;
}

// ---------------------------------------------------------------------------
extern "C" void kernel_launch(void* const* d_in, const int* in_sizes, int n_in,
                              void* d_out, int out_size, void* d_ws, size_t ws_size,
                              hipStream_t stream) {
    const float* img1 = (const float*)d_in[0];
    const float* img2 = (const float*)d_in[1];
    const float* W    = (const float*)d_in[2];
    const float* bias = (const float*)d_in[3];
    float* out = (float*)d_out;

    float* Q = (float*)d_ws;                                   // 2*2*16*1024*512 floats
    const size_t qElems = (size_t)2 * NHEAD * BSZ * SEQ * EMB; // 33,554,432
    float* Zr  = Q + qElems;                                   // each 32*1024 floats
    float* Zc  = Zr + (size_t)NHEAD * BSZ * SEQ;
    float* S21 = Zc + (size_t)NHEAD * BSZ * SEQ;
    float* S12 = S21 + (size_t)NHEAD * BSZ * SEQ;

    // zero Zr/Zc/S21/S12 (contiguous: 4 * 32768 floats)
    zero_kernel<<<dim3(512), dim3(256), 0, stream>>>(Zr, 4 * NHEAD * BSZ * SEQ);

    proj_kernel<<<dim3(SEQ / 128, EMB / 128, 2 * NHEAD * BSZ), dim3(256), 0, stream>>>(
        img1, img2, W, bias, Q);

    norm_kernel<<<dim3(2 * NHEAD * BSZ * SEQ), dim3(128), 0, stream>>>(Q);

    attn_kernel<0><<<dim3(SEQ / 128, SEQ / 128, NHEAD * BSZ), dim3(256), 0, stream>>>(
        Q, Zr, Zc, S21, S12);
    attn_kernel<1><<<dim3(SEQ / 128, SEQ / 128, NHEAD * BSZ), dim3(256), 0, stream>>>(
        Q, Zr, Zc, S21, S12);

    fin_kernel<<<dim3(2 * NHEAD * BSZ), dim3(256), 0, stream>>>(S21, S12, out);
}

// Round 2
// 971.521 us; speedup vs baseline: 2.6466x; 2.6466x over previous
//
#include <hip/hip_runtime.h>
#include <cstdint>
#include <cstddef>

#define INP 2048
#define EMB 512
#define NHEAD 2
#define BSZ 16
#define SEQ 1024
#define LAMBDA 10.0f

typedef __attribute__((ext_vector_type(8))) short bf16x8;
typedef __attribute__((ext_vector_type(4))) float f32x4;

__device__ __forceinline__ short f2bf(float x) {
    union { float f; unsigned u; } v; v.f = x;
    unsigned r = v.u + 0x7fffu + ((v.u >> 16) & 1u);   // RTN-even
    return (short)(r >> 16);
}
__device__ __forceinline__ float bf2f(short h) {
    union { unsigned u; float f; } v; v.u = ((unsigned)(unsigned short)h) << 16;
    return v.f;
}
__device__ __forceinline__ void g2lds16(const void* g, void* l) {
    __builtin_amdgcn_global_load_lds(
        (const __attribute__((address_space(1))) unsigned int*)g,
        (__attribute__((address_space(3))) unsigned int*)l, 16, 0, 0);
}

// ---------------------------------------------------------------------------
__global__ __launch_bounds__(256) void zero_kernel(float* __restrict__ p, int n) {
    int i = blockIdx.x * 256 + threadIdx.x;
    if (i < n) p[i] = 0.f;
}

// ---------------------------------------------------------------------------
// Transpose+convert: src slab [INP][L] fp32 -> out slab [L][INP] bf16 hi/lo.
// grid: (L/32, INP/32, slabs), block 256
// ---------------------------------------------------------------------------
__global__ __launch_bounds__(256) void conv_t(const float* __restrict__ src,
                                              short* __restrict__ hi,
                                              short* __restrict__ lo, int L) {
    const int l0 = blockIdx.x * 32;
    const int d0 = blockIdx.y * 32;
    const float* s = src + (size_t)blockIdx.z * INP * L;
    const size_t obase = (size_t)blockIdx.z * INP * L;

    __shared__ float t[32][33];
    const int tid = threadIdx.x;
    const int r  = tid >> 3;
    const int c4 = (tid & 7) * 4;

    float4 v = *(const float4*)&s[(size_t)(d0 + r) * L + l0 + c4];
    t[r][c4 + 0] = v.x; t[r][c4 + 1] = v.y; t[r][c4 + 2] = v.z; t[r][c4 + 3] = v.w;
    __syncthreads();

    short4 h4, l4;
    float x;
    x = t[c4 + 0][r]; h4.x = f2bf(x); l4.x = f2bf(x - bf2f(h4.x));
    x = t[c4 + 1][r]; h4.y = f2bf(x); l4.y = f2bf(x - bf2f(h4.y));
    x = t[c4 + 2][r]; h4.z = f2bf(x); l4.z = f2bf(x - bf2f(h4.z));
    x = t[c4 + 3][r]; h4.w = f2bf(x); l4.w = f2bf(x - bf2f(h4.w));
    const size_t o = obase + (size_t)(l0 + r) * INP + d0 + c4;
    *(short4*)&hi[o] = h4;
    *(short4*)&lo[o] = l4;
}

// ---------------------------------------------------------------------------
// Split-bf16 MFMA projection: Q[z][l][e] = sum_d x[l][d] W[d][e] + bias (fp32)
// A = imgT chunk [8][SEQ][INP] (hi/lo), B = Wt [NHEAD][EMB][INP] (hi/lo).
// 128x128 tile, BK=32, 4 waves of 64x64, 3-term split MFMA.
// grid: (SEQ/128=8, EMB/128=4, 16), block 256
// ---------------------------------------------------------------------------
__global__ __launch_bounds__(256) void proj_mfma(
    const short* __restrict__ Ahg, const short* __restrict__ Alg,
    const short* __restrict__ Bhg, const short* __restrict__ Blg,
    const float* __restrict__ bias, float* __restrict__ Q, int im, int bbase) {
    const int l0 = blockIdx.x * 128;
    const int e0 = blockIdx.y * 128;
    const int zl = blockIdx.z;
    const int h    = zl >> 3;
    const int bloc = zl & 7;
    const int z = (im * NHEAD + h) * BSZ + bbase + bloc;

    const short* __restrict__ Ah = Ahg + (size_t)bloc * SEQ * INP;
    const short* __restrict__ Al = Alg + (size_t)bloc * SEQ * INP;
    const short* __restrict__ Bh = Bhg + (size_t)h * EMB * INP;
    const short* __restrict__ Bl = Blg + (size_t)h * EMB * INP;

    __shared__ short sAh[128 * 32], sAl[128 * 32], sBh[128 * 32], sBl[128 * 32];

    const int tid  = threadIdx.x;
    const int lane = tid & 63;
    const int wid  = tid >> 6;
    const int srow = lane >> 2;        // 0..15 within staging unit
    const int scol = (lane & 3) * 8;   // k element offset for 16B load
    const int wm = (wid & 1) * 64;
    const int wn = (wid >> 1) * 64;
    const int fm = lane & 15;
    const int fk = (lane >> 4) * 8;

    f32x4 zero4 = {0.f, 0.f, 0.f, 0.f};
    f32x4 acc[4][4];
#pragma unroll
    for (int i = 0; i < 4; i++)
#pragma unroll
        for (int j = 0; j < 4; j++) acc[i][j] = zero4;

    for (int k0 = 0; k0 < INP; k0 += 32) {
        __syncthreads();
#pragma unroll
        for (int u = 0; u < 2; u++) {
            const int unit = wid * 2 + u;        // wave-uniform
            const int row  = unit * 16 + srow;
            const size_t ga = (size_t)(l0 + row) * INP + k0 + scol;
            const size_t gb = (size_t)(e0 + row) * INP + k0 + scol;
            const int lo_off = unit * 512;       // shorts (wave-uniform)
            g2lds16(Ah + ga, sAh + lo_off);
            g2lds16(Al + ga, sAl + lo_off);
            g2lds16(Bh + gb, sBh + lo_off);
            g2lds16(Bl + gb, sBl + lo_off);
        }
        __syncthreads();

        bf16x8 afh[4], afl[4], bfh[4], bfl[4];
#pragma unroll
        for (int i = 0; i < 4; i++) {
            const int r = wm + i * 16 + fm;
            afh[i] = *(const bf16x8*)&sAh[r * 32 + fk];
            afl[i] = *(const bf16x8*)&sAl[r * 32 + fk];
        }
#pragma unroll
        for (int j = 0; j < 4; j++) {
            const int r = wn + j * 16 + fm;
            bfh[j] = *(const bf16x8*)&sBh[r * 32 + fk];
            bfl[j] = *(const bf16x8*)&sBl[r * 32 + fk];
        }
#pragma unroll
        for (int i = 0; i < 4; i++)
#pragma unroll
            for (int j = 0; j < 4; j++) {
                acc[i][j] = __builtin_amdgcn_mfma_f32_16x16x32_bf16(afh[i], bfh[j], acc[i][j], 0, 0, 0);
                acc[i][j] = __builtin_amdgcn_mfma_f32_16x16x32_bf16(afh[i], bfl[j], acc[i][j], 0, 0, 0);
                acc[i][j] = __builtin_amdgcn_mfma_f32_16x16x32_bf16(afl[i], bfh[j], acc[i][j], 0, 0, 0);
            }
    }

    float* __restrict__ Qz = Q + (size_t)z * SEQ * EMB;
    const int quad = lane >> 4;
#pragma unroll
    for (int i = 0; i < 4; i++)
#pragma unroll
        for (int r = 0; r < 4; r++) {
            const int row = l0 + wm + i * 16 + quad * 4 + r;
#pragma unroll
            for (int j = 0; j < 4; j++) {
                const int col = e0 + wn + j * 16 + fm;
                Qz[(size_t)row * EMB + col] = acc[i][j][r] + bias[h * EMB + col];
            }
        }
}

// ---------------------------------------------------------------------------
// Row L2-norm of Q (fp32), fold LAMBDA into n1 (z<32), emit bf16 hi/lo split.
// grid: (SEQ, 64), block 64 (1 wave per row, 8 elems/lane)
// ---------------------------------------------------------------------------
__global__ __launch_bounds__(64) void norm_split(const float* __restrict__ Q,
                                                 short* __restrict__ Qhi,
                                                 short* __restrict__ Qlo) {
    const int z = blockIdx.y;
    const size_t row = (size_t)z * SEQ + blockIdx.x;
    const float* p = Q + row * EMB;
    const int lane = threadIdx.x;

    float4 a = *(const float4*)&p[lane * 8];
    float4 b = *(const float4*)&p[lane * 8 + 4];
    float s = a.x * a.x + a.y * a.y + a.z * a.z + a.w * a.w
            + b.x * b.x + b.y * b.y + b.z * b.z + b.w * b.w;
#pragma unroll
    for (int o = 32; o > 0; o >>= 1) s += __shfl_xor(s, o);
    float scale = 1.f / fmaxf(sqrtf(s), 1e-12f);
    if (z < NHEAD * BSZ) scale *= LAMBDA;

    float v[8] = {a.x * scale, a.y * scale, a.z * scale, a.w * scale,
                  b.x * scale, b.y * scale, b.z * scale, b.w * scale};
    short hv[8], lv[8];
#pragma unroll
    for (int q = 0; q < 8; q++) {
        hv[q] = f2bf(v[q]);
        lv[q] = f2bf(v[q] - bf2f(hv[q]));
    }
    short4 h0 = {hv[0], hv[1], hv[2], hv[3]}, h1 = {hv[4], hv[5], hv[6], hv[7]};
    short4 l0v = {lv[0], lv[1], lv[2], lv[3]}, l1v = {lv[4], lv[5], lv[6], lv[7]};
    *(short4*)&Qhi[row * EMB + lane * 8]     = h0;
    *(short4*)&Qhi[row * EMB + lane * 8 + 4] = h1;
    *(short4*)&Qlo[row * EMB + lane * 8]     = l0v;
    *(short4*)&Qlo[row * EMB + lane * 8 + 4] = l1v;
}

// ---------------------------------------------------------------------------
// Split-bf16 MFMA attention: rel = lambda*cos (lambda folded into n1 side),
// E = exp(rel) stored to global; Zr[l] += row sums; Zc[m] += col sums.
// grid: (8, 8, 32), block 256
// ---------------------------------------------------------------------------
__global__ __launch_bounds__(256) void attn_mfma(
    const short* __restrict__ Qhi, const short* __restrict__ Qlo,
    float* __restrict__ E, float* __restrict__ Zr, float* __restrict__ Zc) {
    const int l0 = blockIdx.x * 128;
    const int m0 = blockIdx.y * 128;
    const int hb = blockIdx.z;
    const short* __restrict__ Ah = Qhi + (size_t)hb * SEQ * EMB;
    const short* __restrict__ Al = Qlo + (size_t)hb * SEQ * EMB;
    const short* __restrict__ Bh = Qhi + (size_t)(NHEAD * BSZ + hb) * SEQ * EMB;
    const short* __restrict__ Bl = Qlo + (size_t)(NHEAD * BSZ + hb) * SEQ * EMB;

    __shared__ short sAh[128 * 32], sAl[128 * 32], sBh[128 * 32], sBl[128 * 32];
    __shared__ float redR[128], redC[128];

    const int tid  = threadIdx.x;
    const int lane = tid & 63;
    const int wid  = tid >> 6;
    const int srow = lane >> 2;
    const int scol = (lane & 3) * 8;
    const int wm = (wid & 1) * 64;
    const int wn = (wid >> 1) * 64;
    const int fm = lane & 15;
    const int fk = (lane >> 4) * 8;

    f32x4 zero4 = {0.f, 0.f, 0.f, 0.f};
    f32x4 acc[4][4];
#pragma unroll
    for (int i = 0; i < 4; i++)
#pragma unroll
        for (int j = 0; j < 4; j++) acc[i][j] = zero4;

    for (int k0 = 0; k0 < EMB; k0 += 32) {
        __syncthreads();
#pragma unroll
        for (int u = 0; u < 2; u++) {
            const int unit = wid * 2 + u;
            const int row  = unit * 16 + srow;
            const size_t ga = (size_t)(l0 + row) * EMB + k0 + scol;
            const size_t gb = (size_t)(m0 + row) * EMB + k0 + scol;
            const int lo_off = unit * 512;
            g2lds16(Ah + ga, sAh + lo_off);
            g2lds16(Al + ga, sAl + lo_off);
            g2lds16(Bh + gb, sBh + lo_off);
            g2lds16(Bl + gb, sBl + lo_off);
        }
        __syncthreads();

        bf16x8 afh[4], afl[4], bfh[4], bfl[4];
#pragma unroll
        for (int i = 0; i < 4; i++) {
            const int r = wm + i * 16 + fm;
            afh[i] = *(const bf16x8*)&sAh[r * 32 + fk];
            afl[i] = *(const bf16x8*)&sAl[r * 32 + fk];
        }
#pragma unroll
        for (int j = 0; j < 4; j++) {
            const int r = wn + j * 16 + fm;
            bfh[j] = *(const bf16x8*)&sBh[r * 32 + fk];
            bfl[j] = *(const bf16x8*)&sBl[r * 32 + fk];
        }
#pragma unroll
        for (int i = 0; i < 4; i++)
#pragma unroll
            for (int j = 0; j < 4; j++) {
                acc[i][j] = __builtin_amdgcn_mfma_f32_16x16x32_bf16(afh[i], bfh[j], acc[i][j], 0, 0, 0);
                acc[i][j] = __builtin_amdgcn_mfma_f32_16x16x32_bf16(afh[i], bfl[j], acc[i][j], 0, 0, 0);
                acc[i][j] = __builtin_amdgcn_mfma_f32_16x16x32_bf16(afl[i], bfh[j], acc[i][j], 0, 0, 0);
            }
    }

    if (tid < 128) { redR[tid] = 0.f; redC[tid] = 0.f; }
    __syncthreads();

    float* __restrict__ Ez = E + (size_t)hb * SEQ * SEQ;
    const int quad = lane >> 4;
    float colp[4] = {0.f, 0.f, 0.f, 0.f};
#pragma unroll
    for (int i = 0; i < 4; i++)
#pragma unroll
        for (int r = 0; r < 4; r++) {
            const int lrow = wm + i * 16 + quad * 4 + r;
            float rowp = 0.f;
#pragma unroll
            for (int j = 0; j < 4; j++) {
                const float ev = expf(acc[i][j][r]);
                Ez[(size_t)(l0 + lrow) * SEQ + m0 + wn + j * 16 + fm] = ev;
                rowp += ev;
                colp[j] += ev;
            }
            atomicAdd(&redR[lrow], rowp);
        }
#pragma unroll
    for (int j = 0; j < 4; j++) atomicAdd(&redC[wn + j * 16 + fm], colp[j]);
    __syncthreads();

    if (tid < 128) {
        atomicAdd(&Zr[hb * SEQ + l0 + tid], redR[tid]);
        atomicAdd(&Zc[hb * SEQ + m0 + tid], redC[tid]);
    }
}

// ---------------------------------------------------------------------------
// Pass 2 (memory-bound): S21[l] = sum_m E[l][m]/Zc[m]; S12[m] = sum_l E[l][m]/Zr[l]
// grid: (8, 32), block 256 (4 waves x 32 rows each)
// ---------------------------------------------------------------------------
__global__ __launch_bounds__(256) void reduce_pass(
    const float* __restrict__ E, const float* __restrict__ Zr,
    const float* __restrict__ Zc, float* __restrict__ S21, float* __restrict__ S12) {
    const int lblk = blockIdx.x;
    const int hb   = blockIdx.y;
    const int tid  = threadIdx.x;
    const int lane = tid & 63;
    const int wid  = tid >> 6;
    const float* __restrict__ Ez = E + (size_t)hb * SEQ * SEQ;

    __shared__ float colred[SEQ];
    for (int i = tid; i < SEQ; i += 256) colred[i] = 0.f;
    __syncthreads();

    float4 izc[4];
#pragma unroll
    for (int it = 0; it < 4; it++) {
        const int m = it * 256 + lane * 4;
        izc[it].x = 1.f / Zc[hb * SEQ + m + 0];
        izc[it].y = 1.f / Zc[hb * SEQ + m + 1];
        izc[it].z = 1.f / Zc[hb * SEQ + m + 2];
        izc[it].w = 1.f / Zc[hb * SEQ + m + 3];
    }
    float4 colacc[4];
#pragma unroll
    for (int it = 0; it < 4; it++) colacc[it] = make_float4(0.f, 0.f, 0.f, 0.f);

    for (int rr = 0; rr < 32; rr++) {
        const int row = lblk * 128 + wid * 32 + rr;
        const float izr = 1.f / Zr[hb * SEQ + row];
        float rowsum = 0.f;
#pragma unroll
        for (int it = 0; it < 4; it++) {
            float4 ev = *(const float4*)&Ez[(size_t)row * SEQ + it * 256 + lane * 4];
            rowsum += ev.x * izc[it].x + ev.y * izc[it].y + ev.z * izc[it].z + ev.w * izc[it].w;
            colacc[it].x += ev.x * izr;
            colacc[it].y += ev.y * izr;
            colacc[it].z += ev.z * izr;
            colacc[it].w += ev.w * izr;
        }
#pragma unroll
        for (int o = 32; o > 0; o >>= 1) rowsum += __shfl_down(rowsum, o);
        if (lane == 0) S21[hb * SEQ + row] = rowsum;
    }
#pragma unroll
    for (int it = 0; it < 4; it++) {
        const int m = it * 256 + lane * 4;
        atomicAdd(&colred[m + 0], colacc[it].x);
        atomicAdd(&colred[m + 1], colacc[it].y);
        atomicAdd(&colred[m + 2], colacc[it].z);
        atomicAdd(&colred[m + 3], colacc[it].w);
    }
    __syncthreads();
    for (int i = tid; i < SEQ; i += 256) atomicAdd(&S12[hb * SEQ + i], colred[i]);
}

// ---------------------------------------------------------------------------
__global__ __launch_bounds__(256) void fin_kernel(
    const float* __restrict__ S21, const float* __restrict__ S12,
    float* __restrict__ out) {
    const int z  = blockIdx.x;
    const int w  = z / (NHEAD * BSZ);
    const int hb = z % (NHEAD * BSZ);
    const float* __restrict__ src = (w == 0 ? S21 : S12) + (size_t)hb * SEQ;
    const int t = threadIdx.x;

    float s = 0.f;
    for (int i = t; i < SEQ; i += 256) s += src[i];
#pragma unroll
    for (int o = 32; o > 0; o >>= 1) s += __shfl_down(s, o);
    __shared__ float red[4];
    if ((t & 63) == 0) red[t >> 6] = s;
    __syncthreads();
    const float total = red[0] + red[1] + red[2] + red[3];
    const float inv = 1.f / (total + 1e-8f);
    for (int i = t; i < SEQ; i += 256)
        out[(size_t)z * SEQ + i] = src[i] * inv;
}

// ---------------------------------------------------------------------------
extern "C" void kernel_launch(void* const* d_in, const int* in_sizes, int n_in,
                              void* d_out, int out_size, void* d_ws, size_t ws_size,
                              hipStream_t stream) {
    const float* img1 = (const float*)d_in[0];
    const float* img2 = (const float*)d_in[1];
    const float* W    = (const float*)d_in[2];
    const float* bias = (const float*)d_in[3];
    float* out = (float*)d_out;

    const size_t QN = (size_t)2 * NHEAD * BSZ * SEQ * EMB;  // 33,554,432
    const size_t WN = (size_t)NHEAD * EMB * INP;            //  2,097,152
    const size_t CN = (size_t)8 * SEQ * INP;                // 16,777,216 (chunk: 8 (im,b) pairs)

    short* Qhi = (short*)d_ws;
    short* Qlo = Qhi + QN;
    short* Wth = Qlo + QN;
    short* Wtl = Wth + WN;
    short* iTh = Wtl + WN;
    short* iTl = iTh + CN;
    float* Q   = (float*)(iTl + CN);   // QN floats; reused as E after norm_split
    float* E   = Q;
    float* Zr  = Q + QN;
    float* Zc  = Zr + (size_t)NHEAD * BSZ * SEQ;
    float* S21 = Zc + (size_t)NHEAD * BSZ * SEQ;
    float* S12 = S21 + (size_t)NHEAD * BSZ * SEQ;

    zero_kernel<<<dim3(512), dim3(256), 0, stream>>>(Zr, 4 * NHEAD * BSZ * SEQ);

    // W[h][d][e] -> Wt[h][e][d] hi/lo
    conv_t<<<dim3(EMB / 32, INP / 32, NHEAD), dim3(256), 0, stream>>>(W, Wth, Wtl, EMB);

    // chunked img transpose-convert + projection
    for (int c = 0; c < 4; c++) {
        const int im = c >> 1;
        const int bbase = (c & 1) * 8;
        const float* img = (im == 0 ? img1 : img2) + (size_t)bbase * INP * SEQ;
        conv_t<<<dim3(SEQ / 32, INP / 32, 8), dim3(256), 0, stream>>>(img, iTh, iTl, SEQ);
        proj_mfma<<<dim3(SEQ / 128, EMB / 128, 16), dim3(256), 0, stream>>>(
            iTh, iTl, Wth, Wtl, bias, Q, im, bbase);
    }

    norm_split<<<dim3(SEQ, 2 * NHEAD * BSZ), dim3(64), 0, stream>>>(Q, Qhi, Qlo);

    attn_mfma<<<dim3(SEQ / 128, SEQ / 128, NHEAD * BSZ), dim3(256), 0, stream>>>(
        Qhi, Qlo, E, Zr, Zc);

    reduce_pass<<<dim3(8, NHEAD * BSZ), dim3(256), 0, stream>>>(E, Zr, Zc, S21, S12);

    fin_kernel<<<dim3(2 * NHEAD * BSZ), dim3(256), 0, stream>>>(S21, S12, out);
    (void)in_sizes; (void)n_in; (void)out_size; (void)ws_size;
}